// Round 11
// baseline (14680.443 us; speedup 1.0000x reference)
//
#include <hip/hip_runtime.h>

#define B_ 64
#define T_ 512
#define D_ 1024
#define H_ 1024
#define NG_ 4096   // 4*H
#define NBLK 256

typedef __attribute__((ext_vector_type(8))) short short8v;  // 8 bf16 = 4 VGPR
typedef __attribute__((ext_vector_type(4))) float f32x4;

// round-to-nearest-even f32 -> bf16 (finite inputs)
static __device__ inline unsigned short f2bf(float f) {
  unsigned u = __float_as_uint(f);
  return (unsigned short)((u + 0x7fffu + ((u >> 16) & 1u)) >> 16);
}
static __device__ inline float bf2f(unsigned short s) {
  return __uint_as_float((unsigned)s << 16);
}

// normal cached 16B load (L1/L2), kept as asm to preserve the counted-vmcnt pipeline
static __device__ inline float4 l2_load4(const float* p) {
  float4 r;
  asm volatile("global_load_dwordx4 %0, %1, off" : "=v"(r) : "v"(p));
  return r;
}
// LLC write-through 4B store (bypass L1/L2 -> no dirty L2 lines, cross-XCD visible)
static __device__ inline void llc_store1(float* p, float v) {
  asm volatile("global_store_dword %0, %1, off sc0 sc1" :: "v"(p), "v"(v) : "memory");
}
#define VMWAIT(N)                                          \
  asm volatile("s_waitcnt vmcnt(" #N ")" ::: "memory");    \
  __builtin_amdgcn_sched_barrier(0);

// per-step L2 invalidate: drop stale h lines so normal loads refill from LLC.
// All waves execute it; per-wave in-order VMEM issue + vmcnt(0) orders the
// wave's subsequent loads after its own inv.
#define INVL2()                                            \
  asm volatile("buffer_inv sc1" ::: "memory");             \
  asm volatile("s_waitcnt vmcnt(0)" ::: "memory");         \
  __builtin_amdgcn_sched_barrier(0);

// acc[i][j] += Q[i] * V[j]
#define FMA44(Q, V)                              \
  acc[0][0] = fmaf((Q).x, (V).x, acc[0][0]);     \
  acc[0][1] = fmaf((Q).x, (V).y, acc[0][1]);     \
  acc[0][2] = fmaf((Q).x, (V).z, acc[0][2]);     \
  acc[0][3] = fmaf((Q).x, (V).w, acc[0][3]);     \
  acc[1][0] = fmaf((Q).y, (V).x, acc[1][0]);     \
  acc[1][1] = fmaf((Q).y, (V).y, acc[1][1]);     \
  acc[1][2] = fmaf((Q).y, (V).z, acc[1][2]);     \
  acc[1][3] = fmaf((Q).y, (V).w, acc[1][3]);     \
  acc[2][0] = fmaf((Q).z, (V).x, acc[2][0]);     \
  acc[2][1] = fmaf((Q).z, (V).y, acc[2][1]);     \
  acc[2][2] = fmaf((Q).z, (V).z, acc[2][2]);     \
  acc[2][3] = fmaf((Q).z, (V).w, acc[2][3]);     \
  acc[3][0] = fmaf((Q).w, (V).x, acc[3][0]);     \
  acc[3][1] = fmaf((Q).w, (V).y, acc[3][1]);     \
  acc[3][2] = fmaf((Q).w, (V).z, acc[3][2]);     \
  acc[3][3] = fmaf((Q).w, (V).w, acc[3][3]);

// ---------------- h transpose helpers ----------------
__global__ __launch_bounds__(256) void k_trans_h_fwd(const float* __restrict__ h,
                                                     float* __restrict__ hT) {
  int idx = blockIdx.x * 256 + threadIdx.x;
  int b = idx & 63;
  int k = idx >> 6;
  hT[idx] = h[b * H_ + k];
}

__global__ __launch_bounds__(256) void k_trans_h_back(const float* __restrict__ hT,
                                                      float* __restrict__ h) {
  int idx = blockIdx.x * 256 + threadIdx.x;
  int k = idx & (H_ - 1);
  int b = idx >> 10;
  h[idx] = hT[k * 64 + b];
}

// ---------------- prep: Wi -> fragment-ordered bf16 hi/lo ----------------
__global__ __launch_bounds__(256) void k_prep_w(const float* __restrict__ Wi,
                                                short8v* __restrict__ wh,
                                                short8v* __restrict__ wl) {
  const int idx = blockIdx.x * 256 + threadIdx.x;   // 524288 total
  const int l = idx & 63;
  const int kt = (idx >> 6) & 31;
  const int nt = idx >> 11;
  const int n = nt * 16 + (l & 15);
  const int k = kt * 32 + ((l >> 4) << 3);
  short8v h, lo;
#pragma unroll
  for (int j = 0; j < 8; ++j) {
    const float v = Wi[(size_t)(k + j) * NG_ + n];
    const unsigned short bh = f2bf(v);
    h[j] = (short)bh;
    lo[j] = (short)f2bf(v - bf2f(bh));
  }
  wh[idx] = h;
  wl[idx] = lo;
}

// ---------------- prep: x chunk -> fragment-ordered bf16 hi/lo ----------------
__global__ __launch_bounds__(256) void k_prep_x(const float* __restrict__ x,
                                                short8v* __restrict__ xh,
                                                short8v* __restrict__ xl,
                                                int t0) {
  const int idx = blockIdx.x * 256 + threadIdx.x;   // tc*8192 total
  const int l = idx & 63;
  const int bt = (idx >> 6) & 3;
  const int kt = (idx >> 8) & 31;
  const int tt = idx >> 13;
  const int b = bt * 16 + (l & 15);
  const int k = kt * 32 + ((l >> 4) << 3);
  const float* p = x + ((size_t)b * T_ + (t0 + tt)) * D_ + k;
  const float4 f0 = *(const float4*)p;
  const float4 f1 = *(const float4*)(p + 4);
  const float v[8] = {f0.x, f0.y, f0.z, f0.w, f1.x, f1.y, f1.z, f1.w};
  short8v h, lo;
#pragma unroll
  for (int j = 0; j < 8; ++j) {
    const unsigned short bh = f2bf(v[j]);
    h[j] = (short)bh;
    lo[j] = (short)f2bf(v[j] - bf2f(bh));
  }
  xh[idx] = h;
  xl[idx] = lo;
}

// ---------------- Gx = x@Wi + bias via MFMA (bf16 hi/lo split) ----------------
__global__ __launch_bounds__(256, 3) void k_gemm(
    const short8v* __restrict__ xh, const short8v* __restrict__ xl,
    const short8v* __restrict__ wh, const short8v* __restrict__ wl,
    const float* __restrict__ bias,
    float* __restrict__ gx) {          // [tc][256][64][16]
  const int tid = threadIdx.x;
  const int l = tid & 63;
  const int w = tid >> 6;
  const int tt = blockIdx.y;
  const int nt0 = blockIdx.x * 16 + w * 4;

  f32x4 acc[4][4];
#pragma unroll
  for (int i = 0; i < 4; ++i)
#pragma unroll
    for (int j = 0; j < 4; ++j) acc[i][j] = (f32x4){0.f, 0.f, 0.f, 0.f};

#pragma unroll 2
  for (int kt = 0; kt < 32; ++kt) {
    short8v ah[4], al[4], bh[4], bl[4];
#pragma unroll
    for (int bt = 0; bt < 4; ++bt) {
      const size_t ix = ((size_t)(tt * 32 + kt) * 4 + bt) * 64 + l;
      ah[bt] = xh[ix];
      al[bt] = xl[ix];
    }
#pragma unroll
    for (int q = 0; q < 4; ++q) {
      const size_t ix = ((size_t)(nt0 + q) * 32 + kt) * 64 + l;
      bh[q] = wh[ix];
      bl[q] = wl[ix];
    }
#pragma unroll
    for (int bt = 0; bt < 4; ++bt)
#pragma unroll
      for (int q = 0; q < 4; ++q) {
        acc[bt][q] = __builtin_amdgcn_mfma_f32_16x16x32_bf16(ah[bt], bh[q], acc[bt][q], 0, 0, 0);
        acc[bt][q] = __builtin_amdgcn_mfma_f32_16x16x32_bf16(al[bt], bh[q], acc[bt][q], 0, 0, 0);
        acc[bt][q] = __builtin_amdgcn_mfma_f32_16x16x32_bf16(ah[bt], bl[q], acc[bt][q], 0, 0, 0);
      }
  }

#pragma unroll
  for (int q = 0; q < 4; ++q) {
    const int n = (nt0 + q) * 16 + (l & 15);
    const int g = n >> 10;
    const int cb = (n & 1023) >> 2;
    const int c = n & 3;
    const float bv = bias[n];
#pragma unroll
    for (int bt = 0; bt < 4; ++bt)
#pragma unroll
      for (int r = 0; r < 4; ++r) {
        const int b = bt * 16 + (l >> 4) * 4 + r;
        gx[(((size_t)tt * 256 + cb) * 64 + b) * 16 + c * 4 + g] = acc[bt][q][r] + bv;
      }
  }
}

// ---------------- persistent recurrence (L2-shared h + 1 inv/step) ----------------
#define RPF16A(HV, KB)                                              \
  _Pragma("unroll") for (int j = 0; j < 16; ++j)                    \
      HV[j] = l2_load4(hin + (size_t)((KB) + j) * 64 + bg4);
#define RCMP16(HV, KB)                                              \
  _Pragma("unroll") for (int j = 0; j < 16; ++j) {                  \
    const float4 wv = *(const float4*)(wlds + ((KB) + j) * 16 + cg4); \
    FMA44(HV[j], wv)                                                \
  }

__global__ __launch_bounds__(512, 2) void k_recur(
    const float* __restrict__ Wh,     // [1024][4096]
    const float* __restrict__ gx,     // [tc][256][64][16] (bias folded)
    float* __restrict__ hA, float* __restrict__ hB,
    float* __restrict__ c_state,      // [64][1024]
    float* __restrict__ ys,           // [64][512][1024]
    unsigned* __restrict__ bar,
    int t0, int tc) {
  extern __shared__ float smem[];
  float* wlds = smem;           // [1024][16], j = c*4 + g
  float* red = smem + 16384;

  const int tid = threadIdx.x;
  const int lane = tid & 63;
  const int w = tid >> 6;
  const int bg = lane & 15;
  const int cg = lane >> 4;
  const int bg4 = bg * 4;
  const int cg4 = cg * 4;
  const int hbase = blockIdx.x * 4;

  for (int idx = tid; idx < 4096; idx += 512) {
    const int k = idx >> 2;
    const int g = idx & 3;
    const float4 v = *(const float4*)(Wh + (size_t)k * NG_ + g * H_ + hbase);
    wlds[k * 16 + 0 + g] = v.x;
    wlds[k * 16 + 4 + g] = v.y;
    wlds[k * 16 + 8 + g] = v.z;
    wlds[k * 16 + 12 + g] = v.w;
  }
  __syncthreads();

  const int k0 = w * 128;
  const int eb = tid >> 2;
  const int ec = tid & 3;

  float c_reg = 0.f;
  float4 gxv = make_float4(0.f, 0.f, 0.f, 0.f);
  if (tid < 256) {
    c_reg = c_state[eb * H_ + hbase + ec];
    gxv = *(const float4*)(gx + ((size_t)blockIdx.x * 64 + eb) * 16 + ec * 4);
  }

  for (int tt = 0; tt < tc; ++tt) {
    const int t = t0 + tt;
    const float* __restrict__ hin = (t & 1) ? hB : hA;
    float* __restrict__ hout = (t & 1) ? hA : hB;

    float acc[4][4];
#pragma unroll
    for (int i = 0; i < 4; ++i)
#pragma unroll
      for (int j = 0; j < 4; ++j) acc[i][j] = 0.f;

    // double-buffered L2-cached loads with counted vmcnt waits
    float4 ha[16], hb[16];
    RPF16A(ha, k0)
    RPF16A(hb, k0 + 16)
    VMWAIT(16)
    RCMP16(ha, k0)       RPF16A(ha, k0 + 32)
    VMWAIT(16)
    RCMP16(hb, k0 + 16)  RPF16A(hb, k0 + 48)
    VMWAIT(16)
    RCMP16(ha, k0 + 32)  RPF16A(ha, k0 + 64)
    VMWAIT(16)
    RCMP16(hb, k0 + 48)  RPF16A(hb, k0 + 80)
    VMWAIT(16)
    RCMP16(ha, k0 + 64)  RPF16A(ha, k0 + 96)
    VMWAIT(16)
    RCMP16(hb, k0 + 80)  RPF16A(hb, k0 + 112)
    VMWAIT(16)
    RCMP16(ha, k0 + 96)
    VMWAIT(0)
    RCMP16(hb, k0 + 112)

#pragma unroll
    for (int i = 0; i < 4; ++i)
#pragma unroll
      for (int j = 0; j < 4; ++j) red[(w * 64 + lane) * 17 + i * 4 + j] = acc[i][j];
    __syncthreads();

    if (tid < 256) {
      const int h = hbase + ec;
      const float* gp = &gxv.x;
      float v[4];
#pragma unroll
      for (int g = 0; g < 4; ++g) {
        float s = gp[g];
#pragma unroll
        for (int ww = 0; ww < 8; ++ww)
          s += red[(ww * 64 + ec * 16 + (eb >> 2)) * 17 + (eb & 3) * 4 + g];
        v[g] = s;
      }
      const float si = 1.f / (1.f + expf(-v[0]));
      const float sf = 1.f / (1.f + expf(-v[1]));
      const float gt = tanhf(v[2]);
      const float so = 1.f / (1.f + expf(-v[3]));
      const float cn = sf * c_reg + si * gt;
      const float hn = so * tanhf(cn);
      c_reg = cn;
      llc_store1(hout + h * 64 + eb, hn);                            // write-through
      llc_store1(ys + (size_t)eb * (T_ * H_) + (size_t)t * H_ + h, hn); // no dirty L2
    }

    // drain own stores to LLC, then barrier (relaxed atomics only)
    asm volatile("s_waitcnt vmcnt(0)" ::: "memory");
    __syncthreads();
    if (tid == 0) {
      __hip_atomic_fetch_add(&bar[(blockIdx.x & 7) << 5], 1u,
                             __ATOMIC_RELAXED, __HIP_MEMORY_SCOPE_AGENT);
    }
    if (tid < 256 && tt + 1 < tc) {   // prefetch next gx under the barrier
      gxv = *(const float4*)(gx +
          ((size_t)((tt + 1) * 256 + blockIdx.x) * 64 + eb) * 16 + ec * 4);
    }
    if (tid == 0) {
      const unsigned tgt = (unsigned)(t + 1);
      if (blockIdx.x == 0) {
        unsigned s;
        do {
          s = 0;
#pragma unroll
          for (int i = 0; i < 8; ++i)
            s += __hip_atomic_load(&bar[i << 5], __ATOMIC_RELAXED,
                                   __HIP_MEMORY_SCOPE_AGENT);
          if (s < (unsigned)NBLK * tgt) __builtin_amdgcn_s_sleep(1);
        } while (s < (unsigned)NBLK * tgt);
        __hip_atomic_store(&bar[256], tgt, __ATOMIC_RELAXED,
                           __HIP_MEMORY_SCOPE_AGENT);
      } else {
        while (__hip_atomic_load(&bar[256], __ATOMIC_RELAXED,
                                 __HIP_MEMORY_SCOPE_AGENT) < tgt)
          __builtin_amdgcn_s_sleep(1);
      }
    }
    __syncthreads();
    // all waves: drop stale h lines from L1/L2 before next step's cached loads
    INVL2()
  }

  if (tid < 256) llc_store1(c_state + eb * H_ + hbase + ec, c_reg);
}

// ---------------- fallback: fused step (tiny ws) ----------------
#define FMA16F(V, W0, W1, W2, W3)               \
  acc[0][0] = fmaf((V), (W0).x, acc[0][0]);     \
  acc[1][0] = fmaf((V), (W0).y, acc[1][0]);     \
  acc[2][0] = fmaf((V), (W0).z, acc[2][0]);     \
  acc[3][0] = fmaf((V), (W0).w, acc[3][0]);     \
  acc[0][1] = fmaf((V), (W1).x, acc[0][1]);     \
  acc[1][1] = fmaf((V), (W1).y, acc[1][1]);     \
  acc[2][1] = fmaf((V), (W1).z, acc[2][1]);     \
  acc[3][1] = fmaf((V), (W1).w, acc[3][1]);     \
  acc[0][2] = fmaf((V), (W2).x, acc[0][2]);     \
  acc[1][2] = fmaf((V), (W2).y, acc[1][2]);     \
  acc[2][2] = fmaf((V), (W2).z, acc[2][2]);     \
  acc[3][2] = fmaf((V), (W2).w, acc[3][2]);     \
  acc[0][3] = fmaf((V), (W3).x, acc[0][3]);     \
  acc[1][3] = fmaf((V), (W3).y, acc[1][3]);     \
  acc[2][3] = fmaf((V), (W3).z, acc[2][3]);     \
  acc[3][3] = fmaf((V), (W3).w, acc[3][3]);

__global__ __launch_bounds__(512, 2) void k_lstm_step_fused(
    const float* __restrict__ xsrc, const float* __restrict__ Wi,
    const float* __restrict__ Wh, const float* __restrict__ bias,
    const float* __restrict__ hT_in, float* __restrict__ hT_out,
    float* __restrict__ c_state, float* __restrict__ ys_t) {
  __shared__ float red[8 * 64 * 17];
  const int tid = threadIdx.x;
  const int lane = tid & 63;
  const int w = tid >> 6;
  const int hbase = blockIdx.x * 4;
  float acc[4][4];
#pragma unroll
  for (int c = 0; c < 4; ++c)
#pragma unroll
    for (int g = 0; g < 4; ++g) acc[c][g] = 0.f;
  const int k0 = w * 128;
#pragma unroll 2
  for (int k = k0; k < k0 + 128; ++k) {
    const float hv = hT_in[k * 64 + lane];
    const float xv = xsrc[(size_t)lane * (T_ * D_) + k];
    const float4 wh0 = *(const float4*)(Wh + (size_t)k * NG_ + 0 * H_ + hbase);
    const float4 wh1 = *(const float4*)(Wh + (size_t)k * NG_ + 1 * H_ + hbase);
    const float4 wh2 = *(const float4*)(Wh + (size_t)k * NG_ + 2 * H_ + hbase);
    const float4 wh3 = *(const float4*)(Wh + (size_t)k * NG_ + 3 * H_ + hbase);
    FMA16F(hv, wh0, wh1, wh2, wh3)
    const float4 wi0 = *(const float4*)(Wi + (size_t)k * NG_ + 0 * H_ + hbase);
    const float4 wi1 = *(const float4*)(Wi + (size_t)k * NG_ + 1 * H_ + hbase);
    const float4 wi2 = *(const float4*)(Wi + (size_t)k * NG_ + 2 * H_ + hbase);
    const float4 wi3 = *(const float4*)(Wi + (size_t)k * NG_ + 3 * H_ + hbase);
    FMA16F(xv, wi0, wi1, wi2, wi3)
  }
#pragma unroll
  for (int c = 0; c < 4; ++c)
#pragma unroll
    for (int g = 0; g < 4; ++g) red[(w * 64 + lane) * 17 + c * 4 + g] = acc[c][g];
  __syncthreads();
  if (tid < 256) {
    const int b = tid >> 2;
    const int c = tid & 3;
    const int h = hbase + c;
    float v[4];
#pragma unroll
    for (int g = 0; g < 4; ++g) {
      float s = bias[g * H_ + h];
#pragma unroll
      for (int ww = 0; ww < 8; ++ww) s += red[(ww * 64 + b) * 17 + c * 4 + g];
      v[g] = s;
    }
    const float cold = c_state[b * H_ + h];
    const float si = 1.f / (1.f + expf(-v[0]));
    const float sf = 1.f / (1.f + expf(-v[1]));
    const float gt = tanhf(v[2]);
    const float so = 1.f / (1.f + expf(-v[3]));
    const float cn = sf * cold + si * gt;
    const float hn = so * tanhf(cn);
    c_state[b * H_ + h] = cn;
    hT_out[h * 64 + b] = hn;
    ys_t[(size_t)b * (T_ * H_) + h] = hn;
  }
}

extern "C" void kernel_launch(void* const* d_in, const int* in_sizes, int n_in,
                              void* d_out, int out_size, void* d_ws, size_t ws_size,
                              hipStream_t stream) {
  const float* c0   = (const float*)d_in[0];
  const float* h0   = (const float*)d_in[1];
  const float* x    = (const float*)d_in[2];
  const float* Wi   = (const float*)d_in[3];
  const float* Wh   = (const float*)d_in[4];
  const float* bias = (const float*)d_in[5];

  float* out     = (float*)d_out;
  float* c_state = out;
  float* h_final = out + B_ * H_;
  float* ys      = out + 2 * B_ * H_;

  const size_t hbytes = (size_t)B_ * H_ * sizeof(float);
  char* ws = (char*)d_ws;
  unsigned* bar = (unsigned*)ws;                        // 8 KB
  float* hA = (float*)(ws + 8192);
  float* hB = (float*)(ws + 8192 + hbytes);
  const size_t wfrag_n = (size_t)256 * 32 * 64;         // 524288 frags
  short8v* wh = (short8v*)(ws + 8192 + 2 * hbytes);     // 8 MB
  short8v* wl = wh + wfrag_n;                           // 8 MB
  char* chunkbase = (char*)(wl + wfrag_n);

  const size_t xfrag_t = (size_t)32 * 4 * 64;           // frags per t
  const size_t per_t = 2 * xfrag_t * sizeof(short8v) + (size_t)256 * 64 * 16 * sizeof(float);
  const size_t fixed = (size_t)(chunkbase - ws);
  size_t avail = (ws_size > fixed) ? ws_size - fixed : 0;
  int Tc = (int)(avail / per_t);
  if (Tc > T_) Tc = T_;

  hipMemsetAsync(bar, 0, 8192, stream);
  hipMemcpyAsync(c_state, c0, hbytes, hipMemcpyDeviceToDevice, stream);
  k_trans_h_fwd<<<B_ * H_ / 256, 256, 0, stream>>>(h0, hA);

  const unsigned smem_recur = (16384 + 8704) * sizeof(float);  // 100352 B

  if (Tc >= 1) {
    k_prep_w<<<2048, 256, 0, stream>>>(Wi, wh, wl);
    for (int t0 = 0; t0 < T_; t0 += Tc) {
      const int tc = (T_ - t0 < Tc) ? (T_ - t0) : Tc;
      short8v* xh = (short8v*)chunkbase;
      short8v* xl = xh + (size_t)tc * xfrag_t;
      float* gxbuf = (float*)(xl + (size_t)tc * xfrag_t);

      k_prep_x<<<tc * 32, 256, 0, stream>>>(x, xh, xl, t0);
      dim3 gg(16, tc);
      k_gemm<<<gg, 256, 0, stream>>>(xh, xl, wh, wl, bias, gxbuf);

      int t0v = t0, tcv = tc;
      void* args[] = {(void*)&Wh,  (void*)&gxbuf,   (void*)&hA,
                      (void*)&hB,  (void*)&c_state, (void*)&ys,
                      (void*)&bar, (void*)&t0v,     (void*)&tcv};
      hipLaunchCooperativeKernel((void*)k_recur, dim3(NBLK), dim3(512), args,
                                 smem_recur, stream);
    }
  } else {
    for (int t = 0; t < T_; ++t) {
      const float* hin = (t & 1) ? hB : hA;
      float* hout      = (t & 1) ? hA : hB;
      k_lstm_step_fused<<<256, 512, 0, stream>>>(
          x + (size_t)t * D_, Wi, Wh, bias, hin, hout, c_state,
          ys + (size_t)t * H_);
    }
  }
  k_trans_h_back<<<B_ * H_ / 256, 256, 0, stream>>>(hA, h_final);
}

// Round 12
// 3418.384 us; speedup vs baseline: 4.2946x; 4.2946x over previous
//
#include <hip/hip_runtime.h>

#define B_ 64
#define T_ 512
#define D_ 1024
#define H_ 1024
#define NG_ 4096   // 4*H
#define NBLK 256

typedef __attribute__((ext_vector_type(8))) short short8v;  // 8 bf16 = 4 VGPR
typedef __attribute__((ext_vector_type(4))) float f32x4;

// round-to-nearest-even f32 -> bf16 (finite inputs)
static __device__ inline unsigned short f2bf(float f) {
  unsigned u = __float_as_uint(f);
  return (unsigned short)((u + 0x7fffu + ((u >> 16) & 1u)) >> 16);
}
static __device__ inline float bf2f(unsigned short s) {
  return __uint_as_float((unsigned)s << 16);
}

// LLC-coherent (cross-XCD) ops: bypass L1/L2 via sc0 sc1.
static __device__ inline float4 llc_load4(const float* p) {
  float4 r;
  asm volatile("global_load_dwordx4 %0, %1, off sc0 sc1" : "=v"(r) : "v"(p));
  return r;
}
static __device__ inline void llc_store1(float* p, float v) {
  asm volatile("global_store_dword %0, %1, off sc0 sc1" :: "v"(p), "v"(v) : "memory");
}
static __device__ inline void llc_store_u16(unsigned short* p, unsigned v) {
  asm volatile("global_store_short %0, %1, off sc0 sc1" :: "v"(p), "v"(v) : "memory");
}
#define VMWAIT(N)                                          \
  asm volatile("s_waitcnt vmcnt(" #N ")" ::: "memory");    \
  __builtin_amdgcn_sched_barrier(0);

// ---------------- h transpose helpers (fallback path only) ----------------
__global__ __launch_bounds__(256) void k_trans_h_fwd(const float* __restrict__ h,
                                                     float* __restrict__ hT) {
  int idx = blockIdx.x * 256 + threadIdx.x;
  int b = idx & 63;
  int k = idx >> 6;
  hT[idx] = h[b * H_ + k];
}

__global__ __launch_bounds__(256) void k_trans_h_back(const float* __restrict__ hT,
                                                      float* __restrict__ h) {
  int idx = blockIdx.x * 256 + threadIdx.x;
  int k = idx & (H_ - 1);
  int b = idx >> 10;
  h[idx] = hT[k * 64 + b];
}

// ---------------- init: h0 -> bf16 A-fragment layout ----------------
// hf[((kt*4+bt)*64 + l)*8 + j] = bf16(h0[b=bt*16+(l&15)][k=kt*32+((l>>4)<<3)+j])
__global__ __launch_bounds__(256) void k_init_hfrag(const float* __restrict__ h0,
                                                    unsigned short* __restrict__ hf) {
  const int idx = blockIdx.x * 256 + threadIdx.x;   // 65536
  const int j = idx & 7;
  const int l = (idx >> 3) & 63;
  const int bt = (idx >> 9) & 3;
  const int kt = idx >> 11;
  const int b = bt * 16 + (l & 15);
  const int k = kt * 32 + ((l >> 4) << 3) + j;
  hf[idx] = f2bf(h0[b * H_ + k]);
}

// ---------------- final h from ys[t=511] ----------------
__global__ __launch_bounds__(256) void k_h_final(const float* __restrict__ ys,
                                                 float* __restrict__ h) {
  const int idx = blockIdx.x * 256 + threadIdx.x;   // 65536
  const int b = idx >> 10;
  const int k = idx & 1023;
  h[idx] = ys[(size_t)b * (T_ * H_) + (size_t)(T_ - 1) * H_ + k];
}

// ---------------- prep: Wi -> fragment-ordered bf16 hi/lo ----------------
__global__ __launch_bounds__(256) void k_prep_w(const float* __restrict__ Wi,
                                                short8v* __restrict__ wh,
                                                short8v* __restrict__ wl) {
  const int idx = blockIdx.x * 256 + threadIdx.x;   // 524288 total
  const int l = idx & 63;
  const int kt = (idx >> 6) & 31;
  const int nt = idx >> 11;
  const int n = nt * 16 + (l & 15);
  const int k = kt * 32 + ((l >> 4) << 3);
  short8v h, lo;
#pragma unroll
  for (int j = 0; j < 8; ++j) {
    const float v = Wi[(size_t)(k + j) * NG_ + n];
    const unsigned short bh = f2bf(v);
    h[j] = (short)bh;
    lo[j] = (short)f2bf(v - bf2f(bh));
  }
  wh[idx] = h;
  wl[idx] = lo;
}

// ---------------- prep: x chunk -> fragment-ordered bf16 hi/lo ----------------
__global__ __launch_bounds__(256) void k_prep_x(const float* __restrict__ x,
                                                short8v* __restrict__ xh,
                                                short8v* __restrict__ xl,
                                                int t0) {
  const int idx = blockIdx.x * 256 + threadIdx.x;   // tc*8192 total
  const int l = idx & 63;
  const int bt = (idx >> 6) & 3;
  const int kt = (idx >> 8) & 31;
  const int tt = idx >> 13;
  const int b = bt * 16 + (l & 15);
  const int k = kt * 32 + ((l >> 4) << 3);
  const float* p = x + ((size_t)b * T_ + (t0 + tt)) * D_ + k;
  const float4 f0 = *(const float4*)p;
  const float4 f1 = *(const float4*)(p + 4);
  const float v[8] = {f0.x, f0.y, f0.z, f0.w, f1.x, f1.y, f1.z, f1.w};
  short8v h, lo;
#pragma unroll
  for (int j = 0; j < 8; ++j) {
    const unsigned short bh = f2bf(v[j]);
    h[j] = (short)bh;
    lo[j] = (short)f2bf(v[j] - bf2f(bh));
  }
  xh[idx] = h;
  xl[idx] = lo;
}

// ---------------- Gx = x@Wi + bias via MFMA (bf16 hi/lo split) ----------------
__global__ __launch_bounds__(256, 3) void k_gemm(
    const short8v* __restrict__ xh, const short8v* __restrict__ xl,
    const short8v* __restrict__ wh, const short8v* __restrict__ wl,
    const float* __restrict__ bias,
    float* __restrict__ gx) {          // [tc][256][64][16]
  const int tid = threadIdx.x;
  const int l = tid & 63;
  const int w = tid >> 6;
  const int tt = blockIdx.y;
  const int nt0 = blockIdx.x * 16 + w * 4;

  f32x4 acc[4][4];
#pragma unroll
  for (int i = 0; i < 4; ++i)
#pragma unroll
    for (int j = 0; j < 4; ++j) acc[i][j] = (f32x4){0.f, 0.f, 0.f, 0.f};

#pragma unroll 2
  for (int kt = 0; kt < 32; ++kt) {
    short8v ah[4], al[4], bh[4], bl[4];
#pragma unroll
    for (int bt = 0; bt < 4; ++bt) {
      const size_t ix = ((size_t)(tt * 32 + kt) * 4 + bt) * 64 + l;
      ah[bt] = xh[ix];
      al[bt] = xl[ix];
    }
#pragma unroll
    for (int q = 0; q < 4; ++q) {
      const size_t ix = ((size_t)(nt0 + q) * 32 + kt) * 64 + l;
      bh[q] = wh[ix];
      bl[q] = wl[ix];
    }
#pragma unroll
    for (int bt = 0; bt < 4; ++bt)
#pragma unroll
      for (int q = 0; q < 4; ++q) {
        acc[bt][q] = __builtin_amdgcn_mfma_f32_16x16x32_bf16(ah[bt], bh[q], acc[bt][q], 0, 0, 0);
        acc[bt][q] = __builtin_amdgcn_mfma_f32_16x16x32_bf16(al[bt], bh[q], acc[bt][q], 0, 0, 0);
        acc[bt][q] = __builtin_amdgcn_mfma_f32_16x16x32_bf16(ah[bt], bl[q], acc[bt][q], 0, 0, 0);
      }
  }

#pragma unroll
  for (int q = 0; q < 4; ++q) {
    const int n = (nt0 + q) * 16 + (l & 15);
    const int g = n >> 10;
    const int cb = (n & 1023) >> 2;
    const int c = n & 3;
    const float bv = bias[n];
#pragma unroll
    for (int bt = 0; bt < 4; ++bt)
#pragma unroll
      for (int r = 0; r < 4; ++r) {
        const int b = bt * 16 + (l >> 4) * 4 + r;
        gx[(((size_t)tt * 256 + cb) * 64 + b) * 16 + c * 4 + g] = acc[bt][q][r] + bv;
      }
  }
}

// ---------------- persistent recurrence: MFMA on bf16 h-fragments ----------------
// 256 blocks x 512 thr (8 waves). Wave w: bt = w&3 (b rows bt*16..+15),
// kt range (w>>2)*16 .. +15. Wh' B-frags (hi/lo bf16) staged in LDS once.
// h carried between steps as bf16 A-frags in ws (sc0 sc1 = LLC-coherent).
__global__ __launch_bounds__(512, 2) void k_recur(
    const float* __restrict__ Wh,     // [1024][4096]
    const float* __restrict__ gx,     // [tc][256][64][16] (bias folded)
    unsigned short* __restrict__ hfA, // h bf16 frags ping [65536]
    unsigned short* __restrict__ hfB, // pong
    float* __restrict__ c_state,      // [64][1024]
    float* __restrict__ ys,           // [64][512][1024]
    unsigned* __restrict__ bar,
    int t0, int tc) {
  extern __shared__ char smemc[];
  short8v* wldsh = (short8v*)smemc;          // 2048 frags = 32 KB
  short8v* wldsl = wldsh + 2048;             // 32 KB
  float* red = (float*)(wldsl + 2048);       // 512*5 floats = 10.25 KB

  const int tid = threadIdx.x;
  const int l = tid & 63;
  const int w = tid >> 6;
  const int bt = w & 3;
  const int kt0 = (w >> 2) * 16;
  const int hbase = blockIdx.x * 4;

  // stage Wh' B-frags: col j=(c*4+g) -> Wh[k][g*H + hbase + c], bf16 hi/lo
  for (int idx = tid; idx < 2048; idx += 512) {
    const int ll = idx & 63;
    const int kt = idx >> 6;
    const int col = ll & 15;
    const int c = col >> 2, g = col & 3;
    const int kb = kt * 32 + ((ll >> 4) << 3);
    short8v hi, lo;
#pragma unroll
    for (int j = 0; j < 8; ++j) {
      const float v = Wh[(size_t)(kb + j) * NG_ + g * H_ + hbase + c];
      const unsigned short bh = f2bf(v);
      hi[j] = (short)bh;
      lo[j] = (short)f2bf(v - bf2f(bh));
    }
    wldsh[idx] = hi;
    wldsl[idx] = lo;
  }
  __syncthreads();

  const int eb = tid >> 2;
  const int ec = tid & 3;
  const int hcol = hbase + ec;
  // epilogue hn -> A-frag scatter address (bf16 units)
  const size_t sOff = (((size_t)((hcol >> 5) * 4 + (eb >> 4)) * 64 +
                        ((((hcol & 31) >> 3) << 4) | (eb & 15))) * 8 + (hcol & 7));
  // epilogue red-read lanes: l' = rowgrp*16 + ec*4 + g
  const int rg = (eb & 15) >> 2;
  const int rr = eb & 3;
  const int rbt = eb >> 4;

  float c_reg = 0.f;
  float4 gxv = make_float4(0.f, 0.f, 0.f, 0.f);
  if (tid < 256) {
    c_reg = c_state[eb * H_ + hbase + ec];
    gxv = *(const float4*)(gx + ((size_t)blockIdx.x * 64 + eb) * 16 + ec * 4);
  }

  for (int tt = 0; tt < tc; ++tt) {
    const int t = t0 + tt;
    const unsigned short* __restrict__ hf_in = (t & 1) ? hfB : hfA;
    unsigned short* __restrict__ hf_out = (t & 1) ? hfA : hfB;

    f32x4 acc = (f32x4){0.f, 0.f, 0.f, 0.f};
    float4 aq[16];
#pragma unroll
    for (int q = 0; q < 16; ++q)
      aq[q] = llc_load4((const float*)(hf_in + (((size_t)(kt0 + q) * 4 + bt) * 64 + l) * 8));

#define STEPQ(Q, VM)                                                   \
    { const short8v bh_ = wldsh[(kt0 + (Q)) * 64 + l];                 \
      const short8v bl_ = wldsl[(kt0 + (Q)) * 64 + l];                 \
      VMWAIT(VM)                                                       \
      const short8v av = __builtin_bit_cast(short8v, aq[Q]);           \
      acc = __builtin_amdgcn_mfma_f32_16x16x32_bf16(av, bh_, acc, 0, 0, 0); \
      acc = __builtin_amdgcn_mfma_f32_16x16x32_bf16(av, bl_, acc, 0, 0, 0); }
    STEPQ(0, 15)  STEPQ(1, 14)  STEPQ(2, 13)  STEPQ(3, 12)
    STEPQ(4, 11)  STEPQ(5, 10)  STEPQ(6, 9)   STEPQ(7, 8)
    STEPQ(8, 7)   STEPQ(9, 6)   STEPQ(10, 5)  STEPQ(11, 4)
    STEPQ(12, 3)  STEPQ(13, 2)  STEPQ(14, 1)  STEPQ(15, 0)
#undef STEPQ

    // cross-k-half reduce via LDS: red[(w*64+l)*5 + r]
#pragma unroll
    for (int r = 0; r < 4; ++r) red[(w * 64 + l) * 5 + r] = acc[r];
    __syncthreads();

    if (tid < 256) {
      const float* gp = &gxv.x;
      float v[4];
#pragma unroll
      for (int g = 0; g < 4; ++g) {
        const int lp = rg * 16 + ec * 4 + g;
        v[g] = gp[g] + red[((0 * 4 + rbt) * 64 + lp) * 5 + rr] +
                       red[((1 * 4 + rbt) * 64 + lp) * 5 + rr];
      }
      const float si = 1.f / (1.f + expf(-v[0]));
      const float sf = 1.f / (1.f + expf(-v[1]));
      const float gt = tanhf(v[2]);
      const float so = 1.f / (1.f + expf(-v[3]));
      const float cn = sf * c_reg + si * gt;
      const float hn = so * tanhf(cn);
      c_reg = cn;
      llc_store_u16(hf_out + sOff, (unsigned)f2bf(hn));   // write-through to LLC
      ys[(size_t)eb * (T_ * H_) + (size_t)t * H_ + hcol] = hn;
    }

    // drain own stores to LLC, then flat barrier (relaxed atomics; R10 protocol)
    asm volatile("s_waitcnt vmcnt(0)" ::: "memory");
    __syncthreads();
    if (tid == 0) {
      __hip_atomic_fetch_add(&bar[(blockIdx.x & 7) << 5], 1u,
                             __ATOMIC_RELAXED, __HIP_MEMORY_SCOPE_AGENT);
    }
    if (tid < 256 && tt + 1 < tc) {   // prefetch next gx under the barrier
      gxv = *(const float4*)(gx +
          ((size_t)((tt + 1) * 256 + blockIdx.x) * 64 + eb) * 16 + ec * 4);
    }
    if (tid == 0) {
      const unsigned tgt = (unsigned)(t + 1);
      if (blockIdx.x == 0) {
        unsigned s;
        do {
          s = 0;
#pragma unroll
          for (int i = 0; i < 8; ++i)
            s += __hip_atomic_load(&bar[i << 5], __ATOMIC_RELAXED,
                                   __HIP_MEMORY_SCOPE_AGENT);
          if (s < (unsigned)NBLK * tgt) __builtin_amdgcn_s_sleep(1);
        } while (s < (unsigned)NBLK * tgt);
        __hip_atomic_store(&bar[256], tgt, __ATOMIC_RELAXED,
                           __HIP_MEMORY_SCOPE_AGENT);
      } else {
        while (__hip_atomic_load(&bar[256], __ATOMIC_RELAXED,
                                 __HIP_MEMORY_SCOPE_AGENT) < tgt)
          __builtin_amdgcn_s_sleep(1);
      }
    }
    __syncthreads();
  }

  if (tid < 256) c_state[eb * H_ + hbase + ec] = c_reg;
}

// ---------------- fallback: fused step (tiny ws) ----------------
#define FMA16F(V, W0, W1, W2, W3)               \
  acc[0][0] = fmaf((V), (W0).x, acc[0][0]);     \
  acc[1][0] = fmaf((V), (W0).y, acc[1][0]);     \
  acc[2][0] = fmaf((V), (W0).z, acc[2][0]);     \
  acc[3][0] = fmaf((V), (W0).w, acc[3][0]);     \
  acc[0][1] = fmaf((V), (W1).x, acc[0][1]);     \
  acc[1][1] = fmaf((V), (W1).y, acc[1][1]);     \
  acc[2][1] = fmaf((V), (W1).z, acc[2][1]);     \
  acc[3][1] = fmaf((V), (W1).w, acc[3][1]);     \
  acc[0][2] = fmaf((V), (W2).x, acc[0][2]);     \
  acc[1][2] = fmaf((V), (W2).y, acc[1][2]);     \
  acc[2][2] = fmaf((V), (W2).z, acc[2][2]);     \
  acc[3][2] = fmaf((V), (W2).w, acc[3][2]);     \
  acc[0][3] = fmaf((V), (W3).x, acc[0][3]);     \
  acc[1][3] = fmaf((V), (W3).y, acc[1][3]);     \
  acc[2][3] = fmaf((V), (W3).z, acc[2][3]);     \
  acc[3][3] = fmaf((V), (W3).w, acc[3][3]);

__global__ __launch_bounds__(512, 2) void k_lstm_step_fused(
    const float* __restrict__ xsrc, const float* __restrict__ Wi,
    const float* __restrict__ Wh, const float* __restrict__ bias,
    const float* __restrict__ hT_in, float* __restrict__ hT_out,
    float* __restrict__ c_state, float* __restrict__ ys_t) {
  __shared__ float red[8 * 64 * 17];
  const int tid = threadIdx.x;
  const int lane = tid & 63;
  const int w = tid >> 6;
  const int hbase = blockIdx.x * 4;
  float acc[4][4];
#pragma unroll
  for (int c = 0; c < 4; ++c)
#pragma unroll
    for (int g = 0; g < 4; ++g) acc[c][g] = 0.f;
  const int k0 = w * 128;
#pragma unroll 2
  for (int k = k0; k < k0 + 128; ++k) {
    const float hv = hT_in[k * 64 + lane];
    const float xv = xsrc[(size_t)lane * (T_ * D_) + k];
    const float4 wh0 = *(const float4*)(Wh + (size_t)k * NG_ + 0 * H_ + hbase);
    const float4 wh1 = *(const float4*)(Wh + (size_t)k * NG_ + 1 * H_ + hbase);
    const float4 wh2 = *(const float4*)(Wh + (size_t)k * NG_ + 2 * H_ + hbase);
    const float4 wh3 = *(const float4*)(Wh + (size_t)k * NG_ + 3 * H_ + hbase);
    FMA16F(hv, wh0, wh1, wh2, wh3)
    const float4 wi0 = *(const float4*)(Wi + (size_t)k * NG_ + 0 * H_ + hbase);
    const float4 wi1 = *(const float4*)(Wi + (size_t)k * NG_ + 1 * H_ + hbase);
    const float4 wi2 = *(const float4*)(Wi + (size_t)k * NG_ + 2 * H_ + hbase);
    const float4 wi3 = *(const float4*)(Wi + (size_t)k * NG_ + 3 * H_ + hbase);
    FMA16F(xv, wi0, wi1, wi2, wi3)
  }
#pragma unroll
  for (int c = 0; c < 4; ++c)
#pragma unroll
    for (int g = 0; g < 4; ++g) red[(w * 64 + lane) * 17 + c * 4 + g] = acc[c][g];
  __syncthreads();
  if (tid < 256) {
    const int b = tid >> 2;
    const int c = tid & 3;
    const int h = hbase + c;
    float v[4];
#pragma unroll
    for (int g = 0; g < 4; ++g) {
      float s = bias[g * H_ + h];
#pragma unroll
      for (int ww = 0; ww < 8; ++ww) s += red[(ww * 64 + b) * 17 + c * 4 + g];
      v[g] = s;
    }
    const float cold = c_state[b * H_ + h];
    const float si = 1.f / (1.f + expf(-v[0]));
    const float sf = 1.f / (1.f + expf(-v[1]));
    const float gt = tanhf(v[2]);
    const float so = 1.f / (1.f + expf(-v[3]));
    const float cn = sf * cold + si * gt;
    const float hn = so * tanhf(cn);
    c_state[b * H_ + h] = cn;
    hT_out[h * 64 + b] = hn;
    ys_t[(size_t)b * (T_ * H_) + h] = hn;
  }
}

extern "C" void kernel_launch(void* const* d_in, const int* in_sizes, int n_in,
                              void* d_out, int out_size, void* d_ws, size_t ws_size,
                              hipStream_t stream) {
  const float* c0   = (const float*)d_in[0];
  const float* h0   = (const float*)d_in[1];
  const float* x    = (const float*)d_in[2];
  const float* Wi   = (const float*)d_in[3];
  const float* Wh   = (const float*)d_in[4];
  const float* bias = (const float*)d_in[5];

  float* out     = (float*)d_out;
  float* c_state = out;
  float* h_final = out + B_ * H_;
  float* ys      = out + 2 * B_ * H_;

  const size_t hbytes = (size_t)B_ * H_ * sizeof(float);   // 256 KB
  char* ws = (char*)d_ws;
  unsigned* bar = (unsigned*)ws;                        // 8 KB
  char* hbufA = ws + 8192;                              // 256 KB (frag bf16 or fp32 hT)
  char* hbufB = hbufA + hbytes;                         // 256 KB
  const size_t wfrag_n = (size_t)256 * 32 * 64;         // 524288 frags
  short8v* wh = (short8v*)(hbufB + hbytes);             // 8 MB
  short8v* wl = wh + wfrag_n;                           // 8 MB
  char* chunkbase = (char*)(wl + wfrag_n);

  const size_t xfrag_t = (size_t)32 * 4 * 64;           // frags per t
  const size_t per_t = 2 * xfrag_t * sizeof(short8v) + (size_t)256 * 64 * 16 * sizeof(float);
  const size_t fixed = (size_t)(chunkbase - ws);
  size_t avail = (ws_size > fixed) ? ws_size - fixed : 0;
  int Tc = (int)(avail / per_t);
  if (Tc > T_) Tc = T_;

  hipMemsetAsync(bar, 0, 8192, stream);
  hipMemcpyAsync(c_state, c0, hbytes, hipMemcpyDeviceToDevice, stream);

  const unsigned smem_recur = 2048 * 16 * 2 + 512 * 5 * 4;   // 75776 B

  if (Tc >= 1) {
    unsigned short* hfA = (unsigned short*)hbufA;
    unsigned short* hfB = (unsigned short*)hbufB;
    k_init_hfrag<<<256, 256, 0, stream>>>(h0, hfA);
    k_prep_w<<<2048, 256, 0, stream>>>(Wi, wh, wl);
    for (int t0 = 0; t0 < T_; t0 += Tc) {
      const int tc = (T_ - t0 < Tc) ? (T_ - t0) : Tc;
      short8v* xh = (short8v*)chunkbase;
      short8v* xl = xh + (size_t)tc * xfrag_t;
      float* gxbuf = (float*)(xl + (size_t)tc * xfrag_t);

      k_prep_x<<<tc * 32, 256, 0, stream>>>(x, xh, xl, t0);
      dim3 gg(16, tc);
      k_gemm<<<gg, 256, 0, stream>>>(xh, xl, wh, wl, bias, gxbuf);

      int t0v = t0, tcv = tc;
      void* args[] = {(void*)&Wh,  (void*)&gxbuf,   (void*)&hfA,
                      (void*)&hfB, (void*)&c_state, (void*)&ys,
                      (void*)&bar, (void*)&t0v,     (void*)&tcv};
      hipLaunchCooperativeKernel((void*)k_recur, dim3(NBLK), dim3(512), args,
                                 smem_recur, stream);
    }
    k_h_final<<<256, 256, 0, stream>>>(ys, h_final);
  } else {
    float* hA = (float*)hbufA;
    float* hB = (float*)hbufB;
    k_trans_h_fwd<<<B_ * H_ / 256, 256, 0, stream>>>(h0, hA);
    for (int t = 0; t < T_; ++t) {
      const float* hin = (t & 1) ? hB : hA;
      float* hout      = (t & 1) ? hA : hB;
      k_lstm_step_fused<<<256, 512, 0, stream>>>(
          x + (size_t)t * D_, Wi, Wh, bias, hin, hout, c_state,
          ys + (size_t)t * H_);
    }
    k_trans_h_back<<<B_ * H_ / 256, 256, 0, stream>>>(hA, h_final);
  }
}